// Round 1
// baseline (129.832 us; speedup 1.0000x reference)
//
#include <hip/hip_runtime.h>
#include <hip/hip_bf16.h>

// Quantization + bit-unpack: out[n, d*B + j] = bit (B-1-j) of (round(x*2^B - 0.5) & 0xFF)
// Memory-bound: 4B in -> 16B out per element (B=4). float4 stores, grid-stride.

__global__ void quant_unpack_b4(const float* __restrict__ x,
                                float* __restrict__ out,
                                long long n) {
    long long i = (long long)blockIdx.x * blockDim.x + threadIdx.x;
    long long stride = (long long)gridDim.x * blockDim.x;
    for (; i < n; i += stride) {
        float v = x[i];
        // match jnp.round (round-half-to-even) via rintf
        int q = ((int)rintf(fmaf(v, 16.0f, -0.5f))) & 0xFF;
        float4 o;
        o.x = (float)((q >> 3) & 1);
        o.y = (float)((q >> 2) & 1);
        o.z = (float)((q >> 1) & 1);
        o.w = (float)(q & 1);
        reinterpret_cast<float4*>(out)[i] = o;
    }
}

__global__ void quant_unpack_gen(const float* __restrict__ x,
                                 float* __restrict__ out,
                                 long long n, int B, float step) {
    long long i = (long long)blockIdx.x * blockDim.x + threadIdx.x;
    long long stride = (long long)gridDim.x * blockDim.x;
    for (; i < n; i += stride) {
        float v = x[i];
        int q = ((int)rintf(fmaf(v, step, -0.5f))) & 0xFF;
        long long base = i * B;
        for (int j = 0; j < B; ++j) {
            out[base + j] = (float)((q >> (B - 1 - j)) & 1);
        }
    }
}

extern "C" void kernel_launch(void* const* d_in, const int* in_sizes, int n_in,
                              void* d_out, int out_size, void* d_ws, size_t ws_size,
                              hipStream_t stream) {
    const float* x = (const float*)d_in[0];
    float* out = (float*)d_out;

    long long n = (long long)in_sizes[0];          // 65536 * 512
    int B = (int)((long long)out_size / n);        // 4

    const int block = 256;
    long long total_blocks = (n + block - 1) / block;
    int grid = (int)(total_blocks < 2048 ? total_blocks : 2048);

    if (B == 4) {
        quant_unpack_b4<<<grid, block, 0, stream>>>(x, out, n);
    } else {
        float step = (float)(1 << B);
        quant_unpack_gen<<<grid, block, 0, stream>>>(x, out, n, B, step);
    }
}

// Round 3
// 126.766 us; speedup vs baseline: 1.0242x; 1.0242x over previous
//
#include <hip/hip_runtime.h>
#include <hip/hip_bf16.h>

// Quantization + bit-unpack: out[n, d*B + j] = bit (B-1-j) of (round(x*2^B - 0.5) & 0xFF)
// Memory-bound: 4B in -> 16B out per element (B=4).
// Nontemporal load/store (native clang vector type -- HIP float4 is rejected
// by __builtin_nontemporal_store): bypass L2 for touch-once streams.

typedef float f32x4 __attribute__((ext_vector_type(4)));

__global__ void quant_unpack_b4(const float* __restrict__ x,
                                float* __restrict__ out,
                                int n) {
    int i = blockIdx.x * blockDim.x + threadIdx.x;
    int stride = gridDim.x * blockDim.x;
    f32x4* __restrict__ out4 = reinterpret_cast<f32x4*>(out);
    for (; i < n; i += stride) {
        float v = __builtin_nontemporal_load(&x[i]);
        // match jnp.round (round-half-to-even) via rintf
        int q = ((int)rintf(fmaf(v, 16.0f, -0.5f))) & 0xFF;
        f32x4 o;
        o.x = (q & 8) ? 1.0f : 0.0f;
        o.y = (q & 4) ? 1.0f : 0.0f;
        o.z = (q & 2) ? 1.0f : 0.0f;
        o.w = (q & 1) ? 1.0f : 0.0f;
        __builtin_nontemporal_store(o, &out4[i]);
    }
}

__global__ void quant_unpack_gen(const float* __restrict__ x,
                                 float* __restrict__ out,
                                 long long n, int B, float step) {
    long long i = (long long)blockIdx.x * blockDim.x + threadIdx.x;
    long long stride = (long long)gridDim.x * blockDim.x;
    for (; i < n; i += stride) {
        float v = x[i];
        int q = ((int)rintf(fmaf(v, step, -0.5f))) & 0xFF;
        long long base = i * B;
        for (int j = 0; j < B; ++j) {
            out[base + j] = (float)((q >> (B - 1 - j)) & 1);
        }
    }
}

extern "C" void kernel_launch(void* const* d_in, const int* in_sizes, int n_in,
                              void* d_out, int out_size, void* d_ws, size_t ws_size,
                              hipStream_t stream) {
    const float* x = (const float*)d_in[0];
    float* out = (float*)d_out;

    long long n = (long long)in_sizes[0];          // 65536 * 512 = 33554432
    int B = (int)((long long)out_size / n);        // 4

    const int block = 256;
    long long total_blocks = (n + block - 1) / block;
    int grid = (int)(total_blocks < 2048 ? total_blocks : 2048);

    if (B == 4 && n <= 0x7FFFFFFFLL) {
        quant_unpack_b4<<<grid, block, 0, stream>>>(x, out, (int)n);
    } else {
        float step = (float)(1 << B);
        quant_unpack_gen<<<grid, block, 0, stream>>>(x, out, n, B, step);
    }
}